// Round 1
// baseline (75.953 us; speedup 1.0000x reference)
//
#include <hip/hip_runtime.h>

// ArithmeticCompute: circle-encoded modular arithmetic over PRIMES.
// out[3][B*S][10][2] = {add, sub, mul} on the unit circle.
//
// Layout: pair = b*S+s in [0, 65536); per pair, 10 primes x (cos,sin).
// Block (64,10): each wave handles ONE prime (threadIdx.y wave-uniform),
// so the per-prime templated code path has no intra-wave divergence.

#define SOFTMAX_TEMP 1000.0f

constexpr double PI_D = 3.14159265358979323846264338327950288;

// Compile-time Taylor trig (args already range-reduced to [-pi, pi]).
constexpr double tay_cos(double x) {
    double x2 = x * x, term = 1.0, sum = 1.0;
    for (int k = 1; k <= 15; ++k) { term *= -x2 / double((2 * k - 1) * (2 * k)); sum += term; }
    return sum;
}
constexpr double tay_sin(double x) {
    double x2 = x * x, term = x, sum = x;
    for (int k = 1; k <= 15; ++k) { term *= -x2 / double((2 * k) * (2 * k + 1)); sum += term; }
    return sum;
}

template <int P> struct Tab { float c[P]; float s[P]; };

template <int P>
constexpr Tab<P> make_tab() {
    Tab<P> t{};
    for (int r = 0; r < P; ++r) {
        double x = 2.0 * PI_D * double(r) / double(P);
        if (x > PI_D) x -= 2.0 * PI_D;  // range-reduce for the Taylor series
        t.c[r] = (float)tay_cos(x);
        t.s[r] = (float)tay_sin(x);
    }
    return t;
}

// mul on the circle via double soft-decode -> residue histogram -> re-encode.
// out = (sum_{i,j} ea[i]*eb[j]*tmpl[(i*j)%P]) / (Sa*Sb)
template <int P>
__device__ __forceinline__ void mul_prime(float ca, float sa, float cb, float sb,
                                          float& oc, float& os) {
    constexpr Tab<P> T = make_tab<P>();

    float ea[P], eb[P];
    float ma = -1e30f, mb = -1e30f;
#pragma unroll
    for (int r = 0; r < P; ++r) {
        float va = ca * T.c[r] + sa * T.s[r];
        float vb = cb * T.c[r] + sb * T.s[r];
        ea[r] = va; eb[r] = vb;
        ma = fmaxf(ma, va); mb = fmaxf(mb, vb);
    }
    float Sa = 0.f, Sb = 0.f;
#pragma unroll
    for (int r = 0; r < P; ++r) {
        float xa = __expf(SOFTMAX_TEMP * (ea[r] - ma));
        float xb = __expf(SOFTMAX_TEMP * (eb[r] - mb));
        ea[r] = xa; Sa += xa;
        eb[r] = xb; Sb += xb;
    }

    // Residue histogram: W[k] = sum over (i*j)%P==k of ea[i]*eb[j].
    float W[P];
#pragma unroll
    for (int k = 0; k < P; ++k) W[k] = 0.f;
    // i==0 row and j==0 column contribute only to k==0 (closed form; also
    // avoids a P-long serial FMA chain on W[0]).
    W[0] = ea[0] * Sb + eb[0] * Sa - ea[0] * eb[0];
#pragma unroll
    for (int i = 1; i < P; ++i) {
#pragma unroll
        for (int j = 1; j < P; ++j) {
            const int k = (i * j) % P;  // compile-time after unroll
            W[k] = fmaf(ea[i], eb[j], W[k]);
        }
    }

    float accC = 0.f, accS = 0.f;
#pragma unroll
    for (int k = 0; k < P; ++k) {
        accC = fmaf(W[k], T.c[k], accC);
        accS = fmaf(W[k], T.s[k], accS);
    }
    float inv = 1.0f / (Sa * Sb);
    oc = accC * inv;
    os = accS * inv;
}

__global__ __launch_bounds__(640) void arith_kernel(const float* __restrict__ a,
                                                    const float* __restrict__ b,
                                                    float* __restrict__ out,
                                                    int n_pairs) {
    const int pair = blockIdx.x * 64 + threadIdx.x;
    const int pi = threadIdx.y;  // prime index, wave-uniform
    if (pair >= n_pairs) return;

    const int base = pair * 20 + pi * 2;
    const float2 av = *(const float2*)(a + base);
    const float2 bv = *(const float2*)(b + base);
    const float ca = av.x, sa = av.y, cb = bv.x, sb = bv.y;

    // add: angles add  -> complex multiply a*b
    // sub: a + conj(b)
    const float pcc = ca * cb, pss = sa * sb, psc = sa * cb, pcs = ca * sb;
    const int plane = n_pairs * 20;
    *(float2*)(out + base)          = make_float2(pcc - pss, psc + pcs);
    *(float2*)(out + plane + base)  = make_float2(pcc + pss, psc - pcs);

    float oc, os;
    switch (pi) {
        case 0: mul_prime<2>(ca, sa, cb, sb, oc, os); break;
        case 1: mul_prime<3>(ca, sa, cb, sb, oc, os); break;
        case 2: mul_prime<5>(ca, sa, cb, sb, oc, os); break;
        case 3: mul_prime<7>(ca, sa, cb, sb, oc, os); break;
        case 4: mul_prime<11>(ca, sa, cb, sb, oc, os); break;
        case 5: mul_prime<13>(ca, sa, cb, sb, oc, os); break;
        case 6: mul_prime<17>(ca, sa, cb, sb, oc, os); break;
        case 7: mul_prime<19>(ca, sa, cb, sb, oc, os); break;
        case 8: mul_prime<23>(ca, sa, cb, sb, oc, os); break;
        default: mul_prime<29>(ca, sa, cb, sb, oc, os); break;
    }
    *(float2*)(out + 2 * plane + base) = make_float2(oc, os);
}

extern "C" void kernel_launch(void* const* d_in, const int* in_sizes, int n_in,
                              void* d_out, int out_size, void* d_ws, size_t ws_size,
                              hipStream_t stream) {
    const float* a = (const float*)d_in[0];
    const float* b = (const float*)d_in[1];
    float* out = (float*)d_out;
    const int n_pairs = in_sizes[0] / 20;  // B*S = 65536

    dim3 block(64, 10);
    dim3 grid((n_pairs + 63) / 64);
    arith_kernel<<<grid, block, 0, stream>>>(a, b, out, n_pairs);
}